// Round 11
// baseline (161.335 us; speedup 1.0000x reference)
//
#include <hip/hip_runtime.h>
#include <hip/hip_bf16.h>
#include <hip/hip_fp16.h>

// GATConv forward (heads=1) + outer ReLU — 3-kernel pipeline + 25KB memset.
//
//  0. hipMemsetAsync(runctr, 0) : runctr is a DELTA counter
//               (gpos = b*CAP_P + old). Replaces the zinit kernel launch.
//  1. pg_k    : [partition ∥ gemm rows 0..49984)]. Partition blocks first
//               (long pole). PC=3072 — interior optimum (R3+R9 both showed
//               shrinking PC costs ~6us: fixed per-block serial scan cost).
//               Partition: packed (src<<8|dst&255) into 391 bucket regions,
//               int4 edge reads, LDS staging -> coalesced pairs writes.
//               GEMM: register-tiled LDS h=x@W (fp16 RNE) + a_src/a_dst.
//  2. cg_k    : [csr counting sort ∥ gemm rows 49984..100K) filler]
//               (R7 win: csr alone ran at 1.5 blocks/CU with nothing to
//               hide its LDS serial chains under).
//  3. gat_node_k : two nodes per wave (half-wave each) when degs<=31.
//               Softmax: 5 half-local shfl_xor rounds (latency-hidden, R5).
//               Gather (R6 win): 8 lanes/edge x uint4 (8 fp16), one shfl
//               pair feeds 4 edges, 8 independent 16B loads in flight;
//               deg-adaptive 4-iter short path when dm<=15 (R8).
//               R11: __launch_bounds__(256) — R8's (256,8) min-waves hint
//               squeezed VGPR 52->32 (seen in R10 counters), which cannot
//               hold 8 in-flight uint4 loads (32 VGPRs alone) and silently
//               serialized the gather, un-doing part of R6's win. At the
//               compiler's natural ~52 VGPR (<=64) occupancy tier is
//               unchanged (8 waves/EU; halving points are 64/128/256).
//               Rare deg>31 -> full-wave fallback.
//               (R1: scattered 4B stores = 64B sector writebacks, +79MB.
//                R2: fusing sort+gather halves gather TLP.
//                R4: pad device-atomic counters to one per 64B line.
//                R5: softmax belongs in gat, latency-hidden, not in csr.
//                R9: do not shrink PC below 3072.)

#define GAT_N 100000
#define GAT_D 64
#define GAT_E 1500000
#define NEG_SLOPE 0.2f
#define NB ((GAT_N + 255) >> 8)            // 391 buckets of 256 nodes
#define PC 3072                            // edges per part block
#define CAP_P 5120                         // pairs capacity/bucket (mean 3840)
#define CAP_C (CAP_P + 256)                // csr capacity/bucket (+self-loops)
#define RPAD 16                            // runctr stride: 1 counter / 64B line
#define GPITCH 68
#define GEMM_BLKS ((GAT_N + 63) / 64)      // 1563
#define G1 (GEMM_BLKS / 2)                 // 781 gemm blocks in pg_k
#define G2 (GEMM_BLKS - G1)                // 782 gemm blocks in cg_k
#define PART_BLKS ((GAT_E + PC - 1) / PC)  // 489

__device__ __forceinline__ float lrelu(float e) {
    return e > 0.f ? e : NEG_SLOPE * e;
}

// ---------------- 1: partition + gemm half 1 ----------------
// LDS union: gemm 4352+4096 = 8448 ints; part 512+256+512+512+512+3072+3072
// = 8448 ints. 33.8KB -> 4 blocks/CU.
__global__ __launch_bounds__(256, 4) void pg_k(
        const float* __restrict__ x, const float* __restrict__ W,
        const float* __restrict__ att_s, const float* __restrict__ att_d,
        unsigned* __restrict__ h, float* __restrict__ a_src, float* __restrict__ a_dst,
        const int* __restrict__ src, const int* __restrict__ dst,
        int* __restrict__ runctr, int* __restrict__ pairs) {
    __shared__ __align__(16) int smem[8448];   // 33.8KB union
    const int t = threadIdx.x;

    if (blockIdx.x >= PART_BLKS) {
        // ---------- GEMM branch (rows [0, G1*64)) ----------
        float* xl = (float*)smem;              // 64*GPITCH = 4352 floats
        float* Wl = (float*)(smem + 4352);     // 4096 floats
        const int rowbase = (blockIdx.x - PART_BLKS) * 64;
        {
            const float4* W4 = (const float4*)W;
            float4* Wl4 = (float4*)Wl;
            #pragma unroll
            for (int i = 0; i < 4; ++i) Wl4[i * 256 + t] = W4[i * 256 + t];
        }
        #pragma unroll
        for (int i = 0; i < 4; ++i) {
            const int g = i * 256 + t;
            const int row = g >> 4, c4 = g & 15;
            float4 v = make_float4(0.f, 0.f, 0.f, 0.f);
            if (rowbase + row < GAT_N)
                v = ((const float4*)x)[(size_t)(rowbase + row) * 16 + c4];
            *(float4*)&xl[row * GPITCH + c4 * 4] = v;
        }
        __syncthreads();

        const int tx = t & 15, ty = t >> 4;
        float4 acc[4] = {};
        #pragma unroll 4
        for (int k0 = 0; k0 < GAT_D; k0 += 4) {
            const float4 w0 = *(const float4*)&Wl[(k0 + 0) * 64 + tx * 4];
            const float4 w1 = *(const float4*)&Wl[(k0 + 1) * 64 + tx * 4];
            const float4 w2 = *(const float4*)&Wl[(k0 + 2) * 64 + tx * 4];
            const float4 w3 = *(const float4*)&Wl[(k0 + 3) * 64 + tx * 4];
            #pragma unroll
            for (int i = 0; i < 4; ++i) {
                const float4 xv = *(const float4*)&xl[(ty * 4 + i) * GPITCH + k0];
                acc[i].x = fmaf(xv.x, w0.x, fmaf(xv.y, w1.x, fmaf(xv.z, w2.x, fmaf(xv.w, w3.x, acc[i].x))));
                acc[i].y = fmaf(xv.x, w0.y, fmaf(xv.y, w1.y, fmaf(xv.z, w2.y, fmaf(xv.w, w3.y, acc[i].y))));
                acc[i].z = fmaf(xv.x, w0.z, fmaf(xv.y, w1.z, fmaf(xv.z, w2.z, fmaf(xv.w, w3.z, acc[i].z))));
                acc[i].w = fmaf(xv.x, w0.w, fmaf(xv.y, w1.w, fmaf(xv.z, w2.w, fmaf(xv.w, w3.w, acc[i].w))));
            }
        }
        const float4 as4 = ((const float4*)att_s)[tx];
        const float4 ad4 = ((const float4*)att_d)[tx];
        #pragma unroll
        for (int i = 0; i < 4; ++i) {
            const int row = rowbase + ty * 4 + i;
            if (row < GAT_N) {
                const __half2 lo = __floats2half2_rn(acc[i].x, acc[i].y);
                const __half2 hi = __floats2half2_rn(acc[i].z, acc[i].w);
                ((uint2*)h)[(size_t)row * 16 + tx] =
                    make_uint2(*(const unsigned*)&lo, *(const unsigned*)&hi);
            }
            float ps = acc[i].x * as4.x + acc[i].y * as4.y + acc[i].z * as4.z + acc[i].w * as4.w;
            float pd = acc[i].x * ad4.x + acc[i].y * ad4.y + acc[i].z * ad4.z + acc[i].w * ad4.w;
            #pragma unroll
            for (int o = 8; o > 0; o >>= 1) {
                ps += __shfl_down(ps, o, 64);
                pd += __shfl_down(pd, o, 64);
            }
            if (tx == 0 && row < GAT_N) { a_src[row] = ps; a_dst[row] = pd; }
        }
    } else {
        // ---------- partition branch (int4-vectorized reads) ----------
        int* lh    = smem;          // 512
        int* sc    = smem + 512;    // 256
        int* lb    = smem + 768;    // 512
        int* gpos  = smem + 1280;   // 512
        int* run   = smem + 1792;   // 512
        int* tgt   = smem + 2304;   // 3072
        int* stage = smem + 5376;   // 3072
        const int base = blockIdx.x * PC;
        const int cnt_total = min(PC, GAT_E - base);   // multiple of 4
        const int nv = cnt_total >> 2;
        const int4* __restrict__ d4p = (const int4*)(dst + base);
        const int4* __restrict__ s4p = (const int4*)(src + base);

        lh[t] = 0; lh[t + 256] = 0;
        __syncthreads();
        for (int i = t; i < nv; i += 256) {
            const int4 d4 = d4p[i];
            atomicAdd(&lh[d4.x >> 8], 1);
            atomicAdd(&lh[d4.y >> 8], 1);
            atomicAdd(&lh[d4.z >> 8], 1);
            atomicAdd(&lh[d4.w >> 8], 1);
        }
        __syncthreads();
        const int a = lh[2 * t], b = lh[2 * t + 1];
        sc[t] = a + b; __syncthreads();
        for (int off = 1; off < 256; off <<= 1) {
            const int xch = (t >= off) ? sc[t - off] : 0;
            __syncthreads();
            sc[t] += xch;
            __syncthreads();
        }
        const int base0 = sc[t] - (a + b);
        lb[2 * t] = base0; lb[2 * t + 1] = base0 + a;
        #pragma unroll
        for (int k = 0; k < 2; ++k) {
            const int i = 2 * t + k;
            run[i] = lb[i];
            // delta counter: absolute gpos = bucket base + old delta
            gpos[i] = (i < NB && lh[i])
                      ? (i * CAP_P + atomicAdd(&runctr[i * RPAD], lh[i])) : 0;
        }
        __syncthreads();
        for (int i = t; i < nv; i += 256) {
            const int4 d4 = d4p[i];
            const int4 s4 = s4p[i];
            #define PART1(SV, DV)                                       \
                {                                                       \
                    const int bk_ = (DV) >> 8;                          \
                    const int slot_ = atomicAdd(&run[bk_], 1);          \
                    stage[slot_] = ((SV) << 8) | ((DV) & 255);          \
                    tgt[slot_] = gpos[bk_] + (slot_ - lb[bk_]);         \
                }
            PART1(s4.x, d4.x) PART1(s4.y, d4.y)
            PART1(s4.z, d4.z) PART1(s4.w, d4.w)
            #undef PART1
        }
        __syncthreads();
        for (int i = t; i < cnt_total; i += 256) pairs[tgt[i]] = stage[i];
    }
}

// ---------------- 2: csr counting sort + gemm half 2 ----------------
// 512 threads. LDS union: csr cnt 256 + pfx 256 + lcsr 5376 = 5888 ints;
// gemm 8448 ints. 33.8KB, 512 thr -> 4 blocks/CU (32 waves).
__global__ __launch_bounds__(512, 8) void cg_k(
        const float* __restrict__ x, const float* __restrict__ W,
        const float* __restrict__ att_s, const float* __restrict__ att_d,
        unsigned* __restrict__ h, float* __restrict__ a_src, float* __restrict__ a_dst,
        const int* __restrict__ pairs, const int* __restrict__ runctr,
        int* __restrict__ rowinfo, int* __restrict__ csr) {
    __shared__ __align__(16) int smem[8448];
    const int t = threadIdx.x;

    if (blockIdx.x < NB) {
        // ---------- csr branch (counting sort) ----------
        int* cnt  = smem;           // 256
        int* pfx  = smem + 256;     // 256
        int* lcsr = smem + 512;     // CAP_C = 5376
        const int b = blockIdx.x;
        const int node0 = b << 8;
        const int nnodes = min(256, GAT_N - node0);
        const int pbeg = b * CAP_P;
        const int ne = runctr[b * RPAD];      // delta counter == edge count
        const int cbase = b * CAP_C;

        if (t < 256) cnt[t] = (t < nnodes) ? 1 : 0;   // self-loop
        __syncthreads();
        for (int i = t; i < ne; i += 512)
            atomicAdd(&cnt[pairs[pbeg + i] & 255], 1);
        __syncthreads();
        if (t < 256) pfx[t] = cnt[t];
        __syncthreads();
        for (int off = 1; off < 256; off <<= 1) {
            const int x2 = (t < 256 && t >= off) ? pfx[t - off] : 0;
            __syncthreads();
            if (t < 256) pfx[t] += x2;
            __syncthreads();
        }
        if (t < 256) {
            const int v = cnt[t];
            const int excl = pfx[t] - v;
            if (t < nnodes) {
                rowinfo[node0 + t] = ((cbase + excl) << 8) | v;   // beg<<8 | deg
                lcsr[excl] = node0 + t;   // self-loop slot 0 of its row
            }
            cnt[t] = excl + ((t < nnodes) ? 1 : 0);
        }
        __syncthreads();
        for (int i = t; i < ne; i += 512) {
            const int p = pairs[pbeg + i];
            const int pos = atomicAdd(&cnt[p & 255], 1);
            lcsr[pos] = p >> 8;
        }
        __syncthreads();
        const int tot = ne + nnodes;
        for (int i = t; i < tot; i += 512) csr[cbase + i] = lcsr[i];
    } else {
        // ---------- GEMM branch (rows [G1*64, 100K), 2 rows/thread) -------
        float* xl = (float*)smem;              // 64*GPITCH = 4352 floats
        float* Wl = (float*)(smem + 4352);     // 4096 floats
        const int rowbase = (G1 + (blockIdx.x - NB)) * 64;
        {
            const float4* W4 = (const float4*)W;
            float4* Wl4 = (float4*)Wl;
            #pragma unroll
            for (int i = 0; i < 2; ++i) Wl4[i * 512 + t] = W4[i * 512 + t];
        }
        #pragma unroll
        for (int i = 0; i < 2; ++i) {
            const int g = i * 512 + t;
            const int row = g >> 4, c4 = g & 15;
            float4 v = make_float4(0.f, 0.f, 0.f, 0.f);
            if (rowbase + row < GAT_N)
                v = ((const float4*)x)[(size_t)(rowbase + row) * 16 + c4];
            *(float4*)&xl[row * GPITCH + c4 * 4] = v;
        }
        __syncthreads();

        const int tx = t & 15, ty = t >> 4;    // ty in [0,32)
        float4 acc[2] = {};
        #pragma unroll 4
        for (int k0 = 0; k0 < GAT_D; k0 += 4) {
            const float4 w0 = *(const float4*)&Wl[(k0 + 0) * 64 + tx * 4];
            const float4 w1 = *(const float4*)&Wl[(k0 + 1) * 64 + tx * 4];
            const float4 w2 = *(const float4*)&Wl[(k0 + 2) * 64 + tx * 4];
            const float4 w3 = *(const float4*)&Wl[(k0 + 3) * 64 + tx * 4];
            #pragma unroll
            for (int i = 0; i < 2; ++i) {
                const float4 xv = *(const float4*)&xl[(ty * 2 + i) * GPITCH + k0];
                acc[i].x = fmaf(xv.x, w0.x, fmaf(xv.y, w1.x, fmaf(xv.z, w2.x, fmaf(xv.w, w3.x, acc[i].x))));
                acc[i].y = fmaf(xv.x, w0.y, fmaf(xv.y, w1.y, fmaf(xv.z, w2.y, fmaf(xv.w, w3.y, acc[i].y))));
                acc[i].z = fmaf(xv.x, w0.z, fmaf(xv.y, w1.z, fmaf(xv.z, w2.z, fmaf(xv.w, w3.z, acc[i].z))));
                acc[i].w = fmaf(xv.x, w0.w, fmaf(xv.y, w1.w, fmaf(xv.z, w2.w, fmaf(xv.w, w3.w, acc[i].w))));
            }
        }
        const float4 as4 = ((const float4*)att_s)[tx];
        const float4 ad4 = ((const float4*)att_d)[tx];
        #pragma unroll
        for (int i = 0; i < 2; ++i) {
            const int row = rowbase + ty * 2 + i;
            if (row < GAT_N) {
                const __half2 lo = __floats2half2_rn(acc[i].x, acc[i].y);
                const __half2 hi = __floats2half2_rn(acc[i].z, acc[i].w);
                ((uint2*)h)[(size_t)row * 16 + tx] =
                    make_uint2(*(const unsigned*)&lo, *(const unsigned*)&hi);
            }
            float ps = acc[i].x * as4.x + acc[i].y * as4.y + acc[i].z * as4.z + acc[i].w * as4.w;
            float pd = acc[i].x * ad4.x + acc[i].y * ad4.y + acc[i].z * ad4.z + acc[i].w * ad4.w;
            #pragma unroll
            for (int o = 8; o > 0; o >>= 1) {
                ps += __shfl_down(ps, o, 64);
                pd += __shfl_down(pd, o, 64);
            }
            if (tx == 0 && row < GAT_N) { a_src[row] = ps; a_dst[row] = pd; }
        }
    }
}

// ---------------- 3: fused per-node GAT ----------------
// Fallback gather (deg>31 path): 16 lanes per edge, uint2 = 4 fp16/lane.
#define GATHER4(ACC, EIDX)                                              \
    {                                                                   \
        const float w_ = __shfl(alpha, (EIDX), 64);                     \
        const int   s_ = __shfl(s, (EIDX), 64);                         \
        const uint2 v_ = h2[(size_t)s_ * 16 + fl];                      \
        const float2 fa_ = __half22float2(*(const __half2*)&v_.x);      \
        const float2 fb_ = __half22float2(*(const __half2*)&v_.y);      \
        ACC.x = fmaf(w_, fa_.x, ACC.x);                                 \
        ACC.y = fmaf(w_, fa_.y, ACC.y);                                 \
        ACC.z = fmaf(w_, fb_.x, ACC.z);                                 \
        ACC.w = fmaf(w_, fb_.y, ACC.w);                                 \
    }

// Full-wave single-node path (fallback for deg > 31; rare).
__device__ __noinline__ void gat_one_node(
        int d, int beg, int deg, int lane,
        const int* __restrict__ csr_src,
        const float* __restrict__ a_src, const float* __restrict__ a_dst,
        const unsigned* __restrict__ h, const float* __restrict__ bias,
        float* __restrict__ out) {
    const int end = beg + deg;
    const float ad = a_dst[d];
    if (deg <= 64) {
        const int k = beg + lane;
        const bool valid = k < end;
        const int s = valid ? csr_src[k] : 0;
        const float e = valid ? lrelu(a_src[s] + ad) : -3.4e38f;
        float m = e;
        #pragma unroll
        for (int o = 32; o > 0; o >>= 1) m = fmaxf(m, __shfl_down(m, o, 64));
        m = __shfl(m, 0, 64);
        const float p = valid ? __expf(e - m) : 0.f;
        float S = p;
        #pragma unroll
        for (int o = 32; o > 0; o >>= 1) S += __shfl_down(S, o, 64);
        S = __shfl(S, 0, 64);
        const float alpha = p / (S + 1e-16f);
        const int q = lane >> 4, fl = lane & 15;
        const uint2* __restrict__ h2 = (const uint2*)h;
        float4 A = {0,0,0,0}, B = {0,0,0,0}, C = {0,0,0,0}, D = {0,0,0,0};
        int j = 0;
        for (; j + 16 <= deg; j += 16) {
            GATHER4(A, j + q);
            GATHER4(B, j + 4 + q);
            GATHER4(C, j + 8 + q);
            GATHER4(D, j + 12 + q);
        }
        if (j < deg)      GATHER4(A, j + q);
        if (j + 4 < deg)  GATHER4(B, j + 4 + q);
        if (j + 8 < deg)  GATHER4(C, j + 8 + q);
        if (j + 12 < deg) GATHER4(D, j + 12 + q);
        float4 acc;
        acc.x = (A.x + B.x) + (C.x + D.x);
        acc.y = (A.y + B.y) + (C.y + D.y);
        acc.z = (A.z + B.z) + (C.z + D.z);
        acc.w = (A.w + B.w) + (C.w + D.w);
        acc.x += __shfl_xor(acc.x, 16, 64); acc.x += __shfl_xor(acc.x, 32, 64);
        acc.y += __shfl_xor(acc.y, 16, 64); acc.y += __shfl_xor(acc.y, 32, 64);
        acc.z += __shfl_xor(acc.z, 16, 64); acc.z += __shfl_xor(acc.z, 32, 64);
        acc.w += __shfl_xor(acc.w, 16, 64); acc.w += __shfl_xor(acc.w, 32, 64);
        if (q == 0) {
            const float4 bi = ((const float4*)bias)[fl];
            float4 o;
            o.x = fmaxf(acc.x + bi.x, 0.f);
            o.y = fmaxf(acc.y + bi.y, 0.f);
            o.z = fmaxf(acc.z + bi.z, 0.f);
            o.w = fmaxf(acc.w + bi.w, 0.f);
            ((float4*)out)[(size_t)d * 16 + fl] = o;
        }
    } else {                              // chunked general path
        float m = -3.4e38f;
        for (int base = beg; base < end; base += 64) {
            const int k = base + lane;
            if (k < end) m = fmaxf(m, lrelu(a_src[csr_src[k]] + ad));
        }
        #pragma unroll
        for (int o = 32; o > 0; o >>= 1) m = fmaxf(m, __shfl_down(m, o, 64));
        m = __shfl(m, 0, 64);
        float S = 0.f;
        for (int base = beg; base < end; base += 64) {
            const int k = base + lane;
            if (k < end) S += __expf(lrelu(a_src[csr_src[k]] + ad) - m);
        }
        #pragma unroll
        for (int o = 32; o > 0; o >>= 1) S += __shfl_down(S, o, 64);
        S = __shfl(S, 0, 64);
        const float inv = 1.f / (S + 1e-16f);
        float acc = 0.f;
        const unsigned short* hb = (const unsigned short*)h;
        for (int base = beg; base < end; base += 64) {
            const int k = base + lane;
            int s = 0; float alpha = 0.f;
            if (k < end) {
                s = csr_src[k];
                alpha = __expf(lrelu(a_src[s] + ad) - m) * inv;
            }
            const int lim = min(64, end - base);
            for (int j2 = 0; j2 < lim; ++j2) {
                const float aj = __shfl(alpha, j2, 64);
                const int   sj = __shfl(s, j2, 64);
                const unsigned short u = hb[(size_t)sj * 64 + lane];
                acc = fmaf(aj, __half2float(*(const __half*)&u), acc);
            }
        }
        const float v = acc + bias[lane];
        out[(size_t)d * GAT_D + lane] = v > 0.f ? v : 0.f;
    }
}

// One gather step: 4 edges/half-wave, one shfl pair serves all 4 groups.
#define GSTEP(I)                                                        \
    {                                                                   \
        const int sl = hb5 + (I) * 4 + g;                               \
        const float w_ = __shfl(alpha, sl, 64);                         \
        const int   s_ = __shfl(s,     sl, 64);                         \
        const uint4 v_ = h4[(size_t)s_ * 8 + f];                        \
        const float2 f0 = __half22float2(*(const __half2*)&v_.x);       \
        const float2 f1 = __half22float2(*(const __half2*)&v_.y);       \
        const float2 f2 = __half22float2(*(const __half2*)&v_.z);       \
        const float2 f3 = __half22float2(*(const __half2*)&v_.w);       \
        aL.x = fmaf(w_, f0.x, aL.x); aL.y = fmaf(w_, f0.y, aL.y);       \
        aL.z = fmaf(w_, f1.x, aL.z); aL.w = fmaf(w_, f1.y, aL.w);       \
        aH.x = fmaf(w_, f2.x, aH.x); aH.y = fmaf(w_, f2.y, aH.y);       \
        aH.z = fmaf(w_, f3.x, aH.z); aH.w = fmaf(w_, f3.y, aH.w);       \
    }

__global__ __launch_bounds__(256) void gat_node_k(
        const int* __restrict__ rowinfo, const int* __restrict__ csr_src,
        const float* __restrict__ a_src, const float* __restrict__ a_dst,
        const unsigned* __restrict__ h, const float* __restrict__ bias,
        float* __restrict__ out) {
    const int pair = blockIdx.x * 4 + (threadIdx.x >> 6);   // N/2 pairs exactly
    const int lane = threadIdx.x & 63;
    const int half = lane >> 5, l32 = lane & 31;
    const int n0 = pair * 2;
    const int n = n0 + half;                 // this half's node (always < N)

    const int ri  = rowinfo[n];
    const int beg = ri >> 8;
    const int deg = ri & 255;
    const int dm  = max(deg, __shfl_xor(deg, 32, 64));   // wave-uniform

    if (dm <= 31) {
        // -------- softmax (latency-hidden under gather; R5 measured) -----
        const float ad = a_dst[n];
        const bool valid = l32 < deg;
        const int k = beg + l32;
        const int s = valid ? csr_src[k] : 0;
        const float e0 = valid ? lrelu(a_src[s] + ad) : -3.4e38f;
        float m = e0;
        #pragma unroll
        for (int o = 16; o > 0; o >>= 1) m = fmaxf(m, __shfl_xor(m, o, 64));
        const float p = valid ? __expf(e0 - m) : 0.f;
        float S = p;
        #pragma unroll
        for (int o = 16; o > 0; o >>= 1) S += __shfl_xor(S, o, 64);
        const float alpha = p / (S + 1e-16f);   // lanes >= deg: 0

        // -------- gather: 8 lanes/edge, 4 edge-groups per half-wave (R6);
        // deg-adaptive 4-iter short path when dm<=15 (R8).
        const int g = l32 >> 3, f = l32 & 7;
        const int hb5 = lane & 32;
        const uint4* __restrict__ h4 = (const uint4*)h;
        float4 aL = {0,0,0,0}, aH = {0,0,0,0};
        if (dm <= 15) {
            #pragma unroll
            for (int i = 0; i < 4; ++i) GSTEP(i);
        } else {
            #pragma unroll
            for (int i = 0; i < 8; ++i) GSTEP(i);
        }
        // reduce across the 4 edge-groups (xor 8,16 stay within the half)
        #pragma unroll
        for (int o = 8; o <= 16; o <<= 1) {
            aL.x += __shfl_xor(aL.x, o, 64); aL.y += __shfl_xor(aL.y, o, 64);
            aL.z += __shfl_xor(aL.z, o, 64); aL.w += __shfl_xor(aL.w, o, 64);
            aH.x += __shfl_xor(aH.x, o, 64); aH.y += __shfl_xor(aH.y, o, 64);
            aH.z += __shfl_xor(aH.z, o, 64); aH.w += __shfl_xor(aH.w, o, 64);
        }
        if (g == 0) {                      // lanes f=0..7 hold the full row
            const float4 bL = ((const float4*)bias)[2 * f];
            const float4 bH = ((const float4*)bias)[2 * f + 1];
            float4 oL, oH;
            oL.x = fmaxf(aL.x + bL.x, 0.f);
            oL.y = fmaxf(aL.y + bL.y, 0.f);
            oL.z = fmaxf(aL.z + bL.z, 0.f);
            oL.w = fmaxf(aL.w + bL.w, 0.f);
            oH.x = fmaxf(aH.x + bH.x, 0.f);
            oH.y = fmaxf(aH.y + bH.y, 0.f);
            oH.z = fmaxf(aH.z + bH.z, 0.f);
            oH.w = fmaxf(aH.w + bH.w, 0.f);
            ((float4*)out)[(size_t)n * 16 + 2 * f]     = oL;
            ((float4*)out)[(size_t)n * 16 + 2 * f + 1] = oH;
        }
    } else {
        // -------- rare fallback: full wave per node, sequential --------
        const int ri0 = rowinfo[n0];
        gat_one_node(n0, ri0 >> 8, ri0 & 255, lane, csr_src, a_src, a_dst, h, bias, out);
        const int ri1 = rowinfo[n0 + 1];
        gat_one_node(n0 + 1, ri1 >> 8, ri1 & 255, lane, csr_src, a_src, a_dst, h, bias, out);
    }
}

extern "C" void kernel_launch(void* const* d_in, const int* in_sizes, int n_in,
                              void* d_out, int out_size, void* d_ws, size_t ws_size,
                              hipStream_t stream) {
    const float* x     = (const float*)d_in[0];
    const int*   ei    = (const int*)  d_in[1];
    const float* W     = (const float*)d_in[2];
    const float* att_s = (const float*)d_in[3];
    const float* att_d = (const float*)d_in[4];
    const float* bias  = (const float*)d_in[5];
    float* out = (float*)d_out;

    // ws layout:
    //   h (fp16, 12.8MB) | a_src[N] | a_dst[N] | pairs[NB*CAP_P] (8MB)
    //   | runctr[NB*RPAD] (25KB) | rowinfo[N] (0.4MB) | csr[NB*CAP_C] (8.4MB)
    unsigned* h      = (unsigned*)d_ws;
    float*  a_src    = (float*)(h + (size_t)GAT_N * 32);
    float*  a_dst    = a_src + GAT_N;
    int*    pairs    = (int*)(a_dst + GAT_N);
    int*    runctr   = pairs + (size_t)NB * CAP_P;
    int*    rowinfo  = runctr + (size_t)NB * RPAD;
    int*    csr      = rowinfo + GAT_N;

    const int* src = ei;
    const int* dst = ei + GAT_E;

    // runctr is a DELTA counter: init 0 (graph-capture-safe async fill).
    hipMemsetAsync(runctr, 0, (size_t)NB * RPAD * sizeof(int), stream);
    pg_k<<<PART_BLKS + G1, 256, 0, stream>>>(
        x, W, att_s, att_d, h, a_src, a_dst, src, dst, runctr, pairs);
    cg_k<<<NB + G2, 512, 0, stream>>>(
        x, W, att_s, att_d, h, a_src, a_dst, pairs, runctr, rowinfo, csr);
    gat_node_k<<<GAT_N / 8, 256, 0, stream>>>(rowinfo, csr, a_src, a_dst, h, bias, out);
}

// Round 12
// 157.331 us; speedup vs baseline: 1.0254x; 1.0254x over previous
//
#include <hip/hip_runtime.h>
#include <hip/hip_bf16.h>
#include <hip/hip_fp16.h>

// GATConv forward (heads=1) + outer ReLU — 3-kernel pipeline + 25KB memset.
// FINAL (R12 = R10 exact revert; best measured 159.4us, vs 180.7 baseline).
//
//  0. hipMemsetAsync(runctr, 0) : runctr is a DELTA counter
//               (gpos = b*CAP_P + old). Replaces the zinit kernel launch.
//  1. pg_k    : [partition ∥ gemm rows 0..49984)]. Partition blocks first
//               (long pole). PC=3072 — interior optimum (R3+R9 both showed
//               shrinking PC costs ~6us: fixed per-block serial scan cost).
//               Partition: packed (src<<8|dst&255) into 391 bucket regions,
//               int4 edge reads, LDS staging -> coalesced pairs writes.
//               GEMM: register-tiled LDS h=x@W (fp16 RNE) + a_src/a_dst.
//  2. cg_k    : [csr counting sort ∥ gemm rows 49984..100K) filler]
//               (R7 win: csr alone ran at 1.5 blocks/CU with nothing to
//               hide its LDS serial chains under).
//  3. gat_node_k : two nodes per wave (half-wave each) when degs<=31.
//               Softmax: 5 half-local shfl_xor rounds (latency-hidden, R5).
//               Gather (R6 win): 8 lanes/edge x uint4 (8 fp16), one shfl
//               pair feeds 4 edges; deg-adaptive 4-iter short path when
//               dm<=15 (R8). __launch_bounds__(256,8): R11 tested dropping
//               the min-waves hint (VGPR 32->52) — came back +1.9us; at 8
//               waves/EU either way, the gather is bound by the memory
//               system's random-16B service rate under full TLP, not
//               per-wave load depth. Keep (256,8).
//               Rare deg>31 -> full-wave fallback.
//               (R1: scattered 4B stores = 64B sector writebacks, +79MB.
//                R2: fusing sort+gather halves gather TLP.
//                R4: pad device-atomic counters to one per 64B line.
//                R5: softmax belongs in gat, latency-hidden, not in csr.
//                R9: do not shrink PC below 3072.)

#define GAT_N 100000
#define GAT_D 64
#define GAT_E 1500000
#define NEG_SLOPE 0.2f
#define NB ((GAT_N + 255) >> 8)            // 391 buckets of 256 nodes
#define PC 3072                            // edges per part block
#define CAP_P 5120                         // pairs capacity/bucket (mean 3840)
#define CAP_C (CAP_P + 256)                // csr capacity/bucket (+self-loops)
#define RPAD 16                            // runctr stride: 1 counter / 64B line
#define GPITCH 68
#define GEMM_BLKS ((GAT_N + 63) / 64)      // 1563
#define G1 (GEMM_BLKS / 2)                 // 781 gemm blocks in pg_k
#define G2 (GEMM_BLKS - G1)                // 782 gemm blocks in cg_k
#define PART_BLKS ((GAT_E + PC - 1) / PC)  // 489

__device__ __forceinline__ float lrelu(float e) {
    return e > 0.f ? e : NEG_SLOPE * e;
}

// ---------------- 1: partition + gemm half 1 ----------------
// LDS union: gemm 4352+4096 = 8448 ints; part 512+256+512+512+512+3072+3072
// = 8448 ints. 33.8KB -> 4 blocks/CU.
__global__ __launch_bounds__(256, 4) void pg_k(
        const float* __restrict__ x, const float* __restrict__ W,
        const float* __restrict__ att_s, const float* __restrict__ att_d,
        unsigned* __restrict__ h, float* __restrict__ a_src, float* __restrict__ a_dst,
        const int* __restrict__ src, const int* __restrict__ dst,
        int* __restrict__ runctr, int* __restrict__ pairs) {
    __shared__ __align__(16) int smem[8448];   // 33.8KB union
    const int t = threadIdx.x;

    if (blockIdx.x >= PART_BLKS) {
        // ---------- GEMM branch (rows [0, G1*64)) ----------
        float* xl = (float*)smem;              // 64*GPITCH = 4352 floats
        float* Wl = (float*)(smem + 4352);     // 4096 floats
        const int rowbase = (blockIdx.x - PART_BLKS) * 64;
        {
            const float4* W4 = (const float4*)W;
            float4* Wl4 = (float4*)Wl;
            #pragma unroll
            for (int i = 0; i < 4; ++i) Wl4[i * 256 + t] = W4[i * 256 + t];
        }
        #pragma unroll
        for (int i = 0; i < 4; ++i) {
            const int g = i * 256 + t;
            const int row = g >> 4, c4 = g & 15;
            float4 v = make_float4(0.f, 0.f, 0.f, 0.f);
            if (rowbase + row < GAT_N)
                v = ((const float4*)x)[(size_t)(rowbase + row) * 16 + c4];
            *(float4*)&xl[row * GPITCH + c4 * 4] = v;
        }
        __syncthreads();

        const int tx = t & 15, ty = t >> 4;
        float4 acc[4] = {};
        #pragma unroll 4
        for (int k0 = 0; k0 < GAT_D; k0 += 4) {
            const float4 w0 = *(const float4*)&Wl[(k0 + 0) * 64 + tx * 4];
            const float4 w1 = *(const float4*)&Wl[(k0 + 1) * 64 + tx * 4];
            const float4 w2 = *(const float4*)&Wl[(k0 + 2) * 64 + tx * 4];
            const float4 w3 = *(const float4*)&Wl[(k0 + 3) * 64 + tx * 4];
            #pragma unroll
            for (int i = 0; i < 4; ++i) {
                const float4 xv = *(const float4*)&xl[(ty * 4 + i) * GPITCH + k0];
                acc[i].x = fmaf(xv.x, w0.x, fmaf(xv.y, w1.x, fmaf(xv.z, w2.x, fmaf(xv.w, w3.x, acc[i].x))));
                acc[i].y = fmaf(xv.x, w0.y, fmaf(xv.y, w1.y, fmaf(xv.z, w2.y, fmaf(xv.w, w3.y, acc[i].y))));
                acc[i].z = fmaf(xv.x, w0.z, fmaf(xv.y, w1.z, fmaf(xv.z, w2.z, fmaf(xv.w, w3.z, acc[i].z))));
                acc[i].w = fmaf(xv.x, w0.w, fmaf(xv.y, w1.w, fmaf(xv.z, w2.w, fmaf(xv.w, w3.w, acc[i].w))));
            }
        }
        const float4 as4 = ((const float4*)att_s)[tx];
        const float4 ad4 = ((const float4*)att_d)[tx];
        #pragma unroll
        for (int i = 0; i < 4; ++i) {
            const int row = rowbase + ty * 4 + i;
            if (row < GAT_N) {
                const __half2 lo = __floats2half2_rn(acc[i].x, acc[i].y);
                const __half2 hi = __floats2half2_rn(acc[i].z, acc[i].w);
                ((uint2*)h)[(size_t)row * 16 + tx] =
                    make_uint2(*(const unsigned*)&lo, *(const unsigned*)&hi);
            }
            float ps = acc[i].x * as4.x + acc[i].y * as4.y + acc[i].z * as4.z + acc[i].w * as4.w;
            float pd = acc[i].x * ad4.x + acc[i].y * ad4.y + acc[i].z * ad4.z + acc[i].w * ad4.w;
            #pragma unroll
            for (int o = 8; o > 0; o >>= 1) {
                ps += __shfl_down(ps, o, 64);
                pd += __shfl_down(pd, o, 64);
            }
            if (tx == 0 && row < GAT_N) { a_src[row] = ps; a_dst[row] = pd; }
        }
    } else {
        // ---------- partition branch (int4-vectorized reads) ----------
        int* lh    = smem;          // 512
        int* sc    = smem + 512;    // 256
        int* lb    = smem + 768;    // 512
        int* gpos  = smem + 1280;   // 512
        int* run   = smem + 1792;   // 512
        int* tgt   = smem + 2304;   // 3072
        int* stage = smem + 5376;   // 3072
        const int base = blockIdx.x * PC;
        const int cnt_total = min(PC, GAT_E - base);   // multiple of 4
        const int nv = cnt_total >> 2;
        const int4* __restrict__ d4p = (const int4*)(dst + base);
        const int4* __restrict__ s4p = (const int4*)(src + base);

        lh[t] = 0; lh[t + 256] = 0;
        __syncthreads();
        for (int i = t; i < nv; i += 256) {
            const int4 d4 = d4p[i];
            atomicAdd(&lh[d4.x >> 8], 1);
            atomicAdd(&lh[d4.y >> 8], 1);
            atomicAdd(&lh[d4.z >> 8], 1);
            atomicAdd(&lh[d4.w >> 8], 1);
        }
        __syncthreads();
        const int a = lh[2 * t], b = lh[2 * t + 1];
        sc[t] = a + b; __syncthreads();
        for (int off = 1; off < 256; off <<= 1) {
            const int xch = (t >= off) ? sc[t - off] : 0;
            __syncthreads();
            sc[t] += xch;
            __syncthreads();
        }
        const int base0 = sc[t] - (a + b);
        lb[2 * t] = base0; lb[2 * t + 1] = base0 + a;
        #pragma unroll
        for (int k = 0; k < 2; ++k) {
            const int i = 2 * t + k;
            run[i] = lb[i];
            // delta counter: absolute gpos = bucket base + old delta
            gpos[i] = (i < NB && lh[i])
                      ? (i * CAP_P + atomicAdd(&runctr[i * RPAD], lh[i])) : 0;
        }
        __syncthreads();
        for (int i = t; i < nv; i += 256) {
            const int4 d4 = d4p[i];
            const int4 s4 = s4p[i];
            #define PART1(SV, DV)                                       \
                {                                                       \
                    const int bk_ = (DV) >> 8;                          \
                    const int slot_ = atomicAdd(&run[bk_], 1);          \
                    stage[slot_] = ((SV) << 8) | ((DV) & 255);          \
                    tgt[slot_] = gpos[bk_] + (slot_ - lb[bk_]);         \
                }
            PART1(s4.x, d4.x) PART1(s4.y, d4.y)
            PART1(s4.z, d4.z) PART1(s4.w, d4.w)
            #undef PART1
        }
        __syncthreads();
        for (int i = t; i < cnt_total; i += 256) pairs[tgt[i]] = stage[i];
    }
}

// ---------------- 2: csr counting sort + gemm half 2 ----------------
// 512 threads. LDS union: csr cnt 256 + pfx 256 + lcsr 5376 = 5888 ints;
// gemm 8448 ints. 33.8KB, 512 thr -> 4 blocks/CU (32 waves).
__global__ __launch_bounds__(512, 8) void cg_k(
        const float* __restrict__ x, const float* __restrict__ W,
        const float* __restrict__ att_s, const float* __restrict__ att_d,
        unsigned* __restrict__ h, float* __restrict__ a_src, float* __restrict__ a_dst,
        const int* __restrict__ pairs, const int* __restrict__ runctr,
        int* __restrict__ rowinfo, int* __restrict__ csr) {
    __shared__ __align__(16) int smem[8448];
    const int t = threadIdx.x;

    if (blockIdx.x < NB) {
        // ---------- csr branch (counting sort) ----------
        int* cnt  = smem;           // 256
        int* pfx  = smem + 256;     // 256
        int* lcsr = smem + 512;     // CAP_C = 5376
        const int b = blockIdx.x;
        const int node0 = b << 8;
        const int nnodes = min(256, GAT_N - node0);
        const int pbeg = b * CAP_P;
        const int ne = runctr[b * RPAD];      // delta counter == edge count
        const int cbase = b * CAP_C;

        if (t < 256) cnt[t] = (t < nnodes) ? 1 : 0;   // self-loop
        __syncthreads();
        for (int i = t; i < ne; i += 512)
            atomicAdd(&cnt[pairs[pbeg + i] & 255], 1);
        __syncthreads();
        if (t < 256) pfx[t] = cnt[t];
        __syncthreads();
        for (int off = 1; off < 256; off <<= 1) {
            const int x2 = (t < 256 && t >= off) ? pfx[t - off] : 0;
            __syncthreads();
            if (t < 256) pfx[t] += x2;
            __syncthreads();
        }
        if (t < 256) {
            const int v = cnt[t];
            const int excl = pfx[t] - v;
            if (t < nnodes) {
                rowinfo[node0 + t] = ((cbase + excl) << 8) | v;   // beg<<8 | deg
                lcsr[excl] = node0 + t;   // self-loop slot 0 of its row
            }
            cnt[t] = excl + ((t < nnodes) ? 1 : 0);
        }
        __syncthreads();
        for (int i = t; i < ne; i += 512) {
            const int p = pairs[pbeg + i];
            const int pos = atomicAdd(&cnt[p & 255], 1);
            lcsr[pos] = p >> 8;
        }
        __syncthreads();
        const int tot = ne + nnodes;
        for (int i = t; i < tot; i += 512) csr[cbase + i] = lcsr[i];
    } else {
        // ---------- GEMM branch (rows [G1*64, 100K), 2 rows/thread) -------
        float* xl = (float*)smem;              // 64*GPITCH = 4352 floats
        float* Wl = (float*)(smem + 4352);     // 4096 floats
        const int rowbase = (G1 + (blockIdx.x - NB)) * 64;
        {
            const float4* W4 = (const float4*)W;
            float4* Wl4 = (float4*)Wl;
            #pragma unroll
            for (int i = 0; i < 2; ++i) Wl4[i * 512 + t] = W4[i * 512 + t];
        }
        #pragma unroll
        for (int i = 0; i < 2; ++i) {
            const int g = i * 512 + t;
            const int row = g >> 4, c4 = g & 15;
            float4 v = make_float4(0.f, 0.f, 0.f, 0.f);
            if (rowbase + row < GAT_N)
                v = ((const float4*)x)[(size_t)(rowbase + row) * 16 + c4];
            *(float4*)&xl[row * GPITCH + c4 * 4] = v;
        }
        __syncthreads();

        const int tx = t & 15, ty = t >> 4;    // ty in [0,32)
        float4 acc[2] = {};
        #pragma unroll 4
        for (int k0 = 0; k0 < GAT_D; k0 += 4) {
            const float4 w0 = *(const float4*)&Wl[(k0 + 0) * 64 + tx * 4];
            const float4 w1 = *(const float4*)&Wl[(k0 + 1) * 64 + tx * 4];
            const float4 w2 = *(const float4*)&Wl[(k0 + 2) * 64 + tx * 4];
            const float4 w3 = *(const float4*)&Wl[(k0 + 3) * 64 + tx * 4];
            #pragma unroll
            for (int i = 0; i < 2; ++i) {
                const float4 xv = *(const float4*)&xl[(ty * 2 + i) * GPITCH + k0];
                acc[i].x = fmaf(xv.x, w0.x, fmaf(xv.y, w1.x, fmaf(xv.z, w2.x, fmaf(xv.w, w3.x, acc[i].x))));
                acc[i].y = fmaf(xv.x, w0.y, fmaf(xv.y, w1.y, fmaf(xv.z, w2.y, fmaf(xv.w, w3.y, acc[i].y))));
                acc[i].z = fmaf(xv.x, w0.z, fmaf(xv.y, w1.z, fmaf(xv.z, w2.z, fmaf(xv.w, w3.z, acc[i].z))));
                acc[i].w = fmaf(xv.x, w0.w, fmaf(xv.y, w1.w, fmaf(xv.z, w2.w, fmaf(xv.w, w3.w, acc[i].w))));
            }
        }
        const float4 as4 = ((const float4*)att_s)[tx];
        const float4 ad4 = ((const float4*)att_d)[tx];
        #pragma unroll
        for (int i = 0; i < 2; ++i) {
            const int row = rowbase + ty * 2 + i;
            if (row < GAT_N) {
                const __half2 lo = __floats2half2_rn(acc[i].x, acc[i].y);
                const __half2 hi = __floats2half2_rn(acc[i].z, acc[i].w);
                ((uint2*)h)[(size_t)row * 16 + tx] =
                    make_uint2(*(const unsigned*)&lo, *(const unsigned*)&hi);
            }
            float ps = acc[i].x * as4.x + acc[i].y * as4.y + acc[i].z * as4.z + acc[i].w * as4.w;
            float pd = acc[i].x * ad4.x + acc[i].y * ad4.y + acc[i].z * ad4.z + acc[i].w * ad4.w;
            #pragma unroll
            for (int o = 8; o > 0; o >>= 1) {
                ps += __shfl_down(ps, o, 64);
                pd += __shfl_down(pd, o, 64);
            }
            if (tx == 0 && row < GAT_N) { a_src[row] = ps; a_dst[row] = pd; }
        }
    }
}

// ---------------- 3: fused per-node GAT ----------------
// Fallback gather (deg>31 path): 16 lanes per edge, uint2 = 4 fp16/lane.
#define GATHER4(ACC, EIDX)                                              \
    {                                                                   \
        const float w_ = __shfl(alpha, (EIDX), 64);                     \
        const int   s_ = __shfl(s, (EIDX), 64);                         \
        const uint2 v_ = h2[(size_t)s_ * 16 + fl];                      \
        const float2 fa_ = __half22float2(*(const __half2*)&v_.x);      \
        const float2 fb_ = __half22float2(*(const __half2*)&v_.y);      \
        ACC.x = fmaf(w_, fa_.x, ACC.x);                                 \
        ACC.y = fmaf(w_, fa_.y, ACC.y);                                 \
        ACC.z = fmaf(w_, fb_.x, ACC.z);                                 \
        ACC.w = fmaf(w_, fb_.y, ACC.w);                                 \
    }

// Full-wave single-node path (fallback for deg > 31; rare).
__device__ __noinline__ void gat_one_node(
        int d, int beg, int deg, int lane,
        const int* __restrict__ csr_src,
        const float* __restrict__ a_src, const float* __restrict__ a_dst,
        const unsigned* __restrict__ h, const float* __restrict__ bias,
        float* __restrict__ out) {
    const int end = beg + deg;
    const float ad = a_dst[d];
    if (deg <= 64) {
        const int k = beg + lane;
        const bool valid = k < end;
        const int s = valid ? csr_src[k] : 0;
        const float e = valid ? lrelu(a_src[s] + ad) : -3.4e38f;
        float m = e;
        #pragma unroll
        for (int o = 32; o > 0; o >>= 1) m = fmaxf(m, __shfl_down(m, o, 64));
        m = __shfl(m, 0, 64);
        const float p = valid ? __expf(e - m) : 0.f;
        float S = p;
        #pragma unroll
        for (int o = 32; o > 0; o >>= 1) S += __shfl_down(S, o, 64);
        S = __shfl(S, 0, 64);
        const float alpha = p / (S + 1e-16f);
        const int q = lane >> 4, fl = lane & 15;
        const uint2* __restrict__ h2 = (const uint2*)h;
        float4 A = {0,0,0,0}, B = {0,0,0,0}, C = {0,0,0,0}, D = {0,0,0,0};
        int j = 0;
        for (; j + 16 <= deg; j += 16) {
            GATHER4(A, j + q);
            GATHER4(B, j + 4 + q);
            GATHER4(C, j + 8 + q);
            GATHER4(D, j + 12 + q);
        }
        if (j < deg)      GATHER4(A, j + q);
        if (j + 4 < deg)  GATHER4(B, j + 4 + q);
        if (j + 8 < deg)  GATHER4(C, j + 8 + q);
        if (j + 12 < deg) GATHER4(D, j + 12 + q);
        float4 acc;
        acc.x = (A.x + B.x) + (C.x + D.x);
        acc.y = (A.y + B.y) + (C.y + D.y);
        acc.z = (A.z + B.z) + (C.z + D.z);
        acc.w = (A.w + B.w) + (C.w + D.w);
        acc.x += __shfl_xor(acc.x, 16, 64); acc.x += __shfl_xor(acc.x, 32, 64);
        acc.y += __shfl_xor(acc.y, 16, 64); acc.y += __shfl_xor(acc.y, 32, 64);
        acc.z += __shfl_xor(acc.z, 16, 64); acc.z += __shfl_xor(acc.z, 32, 64);
        acc.w += __shfl_xor(acc.w, 16, 64); acc.w += __shfl_xor(acc.w, 32, 64);
        if (q == 0) {
            const float4 bi = ((const float4*)bias)[fl];
            float4 o;
            o.x = fmaxf(acc.x + bi.x, 0.f);
            o.y = fmaxf(acc.y + bi.y, 0.f);
            o.z = fmaxf(acc.z + bi.z, 0.f);
            o.w = fmaxf(acc.w + bi.w, 0.f);
            ((float4*)out)[(size_t)d * 16 + fl] = o;
        }
    } else {                              // chunked general path
        float m = -3.4e38f;
        for (int base = beg; base < end; base += 64) {
            const int k = base + lane;
            if (k < end) m = fmaxf(m, lrelu(a_src[csr_src[k]] + ad));
        }
        #pragma unroll
        for (int o = 32; o > 0; o >>= 1) m = fmaxf(m, __shfl_down(m, o, 64));
        m = __shfl(m, 0, 64);
        float S = 0.f;
        for (int base = beg; base < end; base += 64) {
            const int k = base + lane;
            if (k < end) S += __expf(lrelu(a_src[csr_src[k]] + ad) - m);
        }
        #pragma unroll
        for (int o = 32; o > 0; o >>= 1) S += __shfl_down(S, o, 64);
        S = __shfl(S, 0, 64);
        const float inv = 1.f / (S + 1e-16f);
        float acc = 0.f;
        const unsigned short* hb = (const unsigned short*)h;
        for (int base = beg; base < end; base += 64) {
            const int k = base + lane;
            int s = 0; float alpha = 0.f;
            if (k < end) {
                s = csr_src[k];
                alpha = __expf(lrelu(a_src[s] + ad) - m) * inv;
            }
            const int lim = min(64, end - base);
            for (int j2 = 0; j2 < lim; ++j2) {
                const float aj = __shfl(alpha, j2, 64);
                const int   sj = __shfl(s, j2, 64);
                const unsigned short u = hb[(size_t)sj * 64 + lane];
                acc = fmaf(aj, __half2float(*(const __half*)&u), acc);
            }
        }
        const float v = acc + bias[lane];
        out[(size_t)d * GAT_D + lane] = v > 0.f ? v : 0.f;
    }
}

// One gather step: 4 edges/half-wave, one shfl pair serves all 4 groups.
#define GSTEP(I)                                                        \
    {                                                                   \
        const int sl = hb5 + (I) * 4 + g;                               \
        const float w_ = __shfl(alpha, sl, 64);                         \
        const int   s_ = __shfl(s,     sl, 64);                         \
        const uint4 v_ = h4[(size_t)s_ * 8 + f];                        \
        const float2 f0 = __half22float2(*(const __half2*)&v_.x);       \
        const float2 f1 = __half22float2(*(const __half2*)&v_.y);       \
        const float2 f2 = __half22float2(*(const __half2*)&v_.z);       \
        const float2 f3 = __half22float2(*(const __half2*)&v_.w);       \
        aL.x = fmaf(w_, f0.x, aL.x); aL.y = fmaf(w_, f0.y, aL.y);       \
        aL.z = fmaf(w_, f1.x, aL.z); aL.w = fmaf(w_, f1.y, aL.w);       \
        aH.x = fmaf(w_, f2.x, aH.x); aH.y = fmaf(w_, f2.y, aH.y);       \
        aH.z = fmaf(w_, f3.x, aH.z); aH.w = fmaf(w_, f3.y, aH.w);       \
    }

__global__ __launch_bounds__(256, 8) void gat_node_k(
        const int* __restrict__ rowinfo, const int* __restrict__ csr_src,
        const float* __restrict__ a_src, const float* __restrict__ a_dst,
        const unsigned* __restrict__ h, const float* __restrict__ bias,
        float* __restrict__ out) {
    const int pair = blockIdx.x * 4 + (threadIdx.x >> 6);   // N/2 pairs exactly
    const int lane = threadIdx.x & 63;
    const int half = lane >> 5, l32 = lane & 31;
    const int n0 = pair * 2;
    const int n = n0 + half;                 // this half's node (always < N)

    const int ri  = rowinfo[n];
    const int beg = ri >> 8;
    const int deg = ri & 255;
    const int dm  = max(deg, __shfl_xor(deg, 32, 64));   // wave-uniform

    if (dm <= 31) {
        // -------- softmax (latency-hidden under gather; R5 measured) -----
        const float ad = a_dst[n];
        const bool valid = l32 < deg;
        const int k = beg + l32;
        const int s = valid ? csr_src[k] : 0;
        const float e0 = valid ? lrelu(a_src[s] + ad) : -3.4e38f;
        float m = e0;
        #pragma unroll
        for (int o = 16; o > 0; o >>= 1) m = fmaxf(m, __shfl_xor(m, o, 64));
        const float p = valid ? __expf(e0 - m) : 0.f;
        float S = p;
        #pragma unroll
        for (int o = 16; o > 0; o >>= 1) S += __shfl_xor(S, o, 64);
        const float alpha = p / (S + 1e-16f);   // lanes >= deg: 0

        // -------- gather: 8 lanes/edge, 4 edge-groups per half-wave (R6);
        // deg-adaptive 4-iter short path when dm<=15 (R8).
        const int g = l32 >> 3, f = l32 & 7;
        const int hb5 = lane & 32;
        const uint4* __restrict__ h4 = (const uint4*)h;
        float4 aL = {0,0,0,0}, aH = {0,0,0,0};
        if (dm <= 15) {
            #pragma unroll
            for (int i = 0; i < 4; ++i) GSTEP(i);
        } else {
            #pragma unroll
            for (int i = 0; i < 8; ++i) GSTEP(i);
        }
        // reduce across the 4 edge-groups (xor 8,16 stay within the half)
        #pragma unroll
        for (int o = 8; o <= 16; o <<= 1) {
            aL.x += __shfl_xor(aL.x, o, 64); aL.y += __shfl_xor(aL.y, o, 64);
            aL.z += __shfl_xor(aL.z, o, 64); aL.w += __shfl_xor(aL.w, o, 64);
            aH.x += __shfl_xor(aH.x, o, 64); aH.y += __shfl_xor(aH.y, o, 64);
            aH.z += __shfl_xor(aH.z, o, 64); aH.w += __shfl_xor(aH.w, o, 64);
        }
        if (g == 0) {                      // lanes f=0..7 hold the full row
            const float4 bL = ((const float4*)bias)[2 * f];
            const float4 bH = ((const float4*)bias)[2 * f + 1];
            float4 oL, oH;
            oL.x = fmaxf(aL.x + bL.x, 0.f);
            oL.y = fmaxf(aL.y + bL.y, 0.f);
            oL.z = fmaxf(aL.z + bL.z, 0.f);
            oL.w = fmaxf(aL.w + bL.w, 0.f);
            oH.x = fmaxf(aH.x + bH.x, 0.f);
            oH.y = fmaxf(aH.y + bH.y, 0.f);
            oH.z = fmaxf(aH.z + bH.z, 0.f);
            oH.w = fmaxf(aH.w + bH.w, 0.f);
            ((float4*)out)[(size_t)n * 16 + 2 * f]     = oL;
            ((float4*)out)[(size_t)n * 16 + 2 * f + 1] = oH;
        }
    } else {
        // -------- rare fallback: full wave per node, sequential --------
        const int ri0 = rowinfo[n0];
        gat_one_node(n0, ri0 >> 8, ri0 & 255, lane, csr_src, a_src, a_dst, h, bias, out);
        const int ri1 = rowinfo[n0 + 1];
        gat_one_node(n0 + 1, ri1 >> 8, ri1 & 255, lane, csr_src, a_src, a_dst, h, bias, out);
    }
}

extern "C" void kernel_launch(void* const* d_in, const int* in_sizes, int n_in,
                              void* d_out, int out_size, void* d_ws, size_t ws_size,
                              hipStream_t stream) {
    const float* x     = (const float*)d_in[0];
    const int*   ei    = (const int*)  d_in[1];
    const float* W     = (const float*)d_in[2];
    const float* att_s = (const float*)d_in[3];
    const float* att_d = (const float*)d_in[4];
    const float* bias  = (const float*)d_in[5];
    float* out = (float*)d_out;

    // ws layout:
    //   h (fp16, 12.8MB) | a_src[N] | a_dst[N] | pairs[NB*CAP_P] (8MB)
    //   | runctr[NB*RPAD] (25KB) | rowinfo[N] (0.4MB) | csr[NB*CAP_C] (8.4MB)
    unsigned* h      = (unsigned*)d_ws;
    float*  a_src    = (float*)(h + (size_t)GAT_N * 32);
    float*  a_dst    = a_src + GAT_N;
    int*    pairs    = (int*)(a_dst + GAT_N);
    int*    runctr   = pairs + (size_t)NB * CAP_P;
    int*    rowinfo  = runctr + (size_t)NB * RPAD;
    int*    csr      = rowinfo + GAT_N;

    const int* src = ei;
    const int* dst = ei + GAT_E;

    // runctr is a DELTA counter: init 0 (graph-capture-safe async fill).
    hipMemsetAsync(runctr, 0, (size_t)NB * RPAD * sizeof(int), stream);
    pg_k<<<PART_BLKS + G1, 256, 0, stream>>>(
        x, W, att_s, att_d, h, a_src, a_dst, src, dst, runctr, pairs);
    cg_k<<<NB + G2, 512, 0, stream>>>(
        x, W, att_s, att_d, h, a_src, a_dst, pairs, runctr, rowinfo, csr);
    gat_node_k<<<GAT_N / 8, 256, 0, stream>>>(rowinfo, csr, a_src, a_dst, h, bias, out);
}